// Round 6
// baseline (974.214 us; speedup 1.0000x reference)
//
#include <hip/hip_runtime.h>
#include <hip/hip_bf16.h>
#include <stdint.h>

// Problem dims (fixed by reference)
#define Bq    8192
#define Hh    8
#define Dd    16
#define Kk    16
#define Nn    4096
#define DFf   16
#define ROWS  (Bq*Hh)          // 65536
#define COLS  (Dd*Kk)          // 256
#define EPSF  1e-6f

typedef unsigned long long u64;
typedef unsigned int u32;
typedef __attribute__((ext_vector_type(8))) short bf16x8;
typedef __attribute__((ext_vector_type(4))) float f32x4;

// async global->LDS, 16B per lane; LDS dest = wave-uniform base + lane*16
#define GLOAD_LDS(g, l) __builtin_amdgcn_global_load_lds( \
    (const __attribute__((address_space(1))) u32*)(g), \
    (__attribute__((address_space(3))) u32*)(l), 16, 0, 0)

// ---------- helpers ----------
__device__ __forceinline__ float dot4(float4 a, float4 b) {
    return fmaf(a.x, b.x, fmaf(a.y, b.y, fmaf(a.z, b.z, a.w * b.w)));
}
__device__ __forceinline__ float wave_sum(float v) {
    #pragma unroll
    for (int m = 32; m > 0; m >>= 1) v += __shfl_xor(v, m, 64);
    return v;
}
__device__ __forceinline__ u32 f32_sortable(float f) {
    u32 u = __float_as_uint(f);
    return (u & 0x80000000u) ? ~u : (u | 0x80000000u);
}
// pack 2 floats -> 2 bf16 (RNE); low 16 bits = a
__device__ __forceinline__ u32 pk2(float a, float b) {
    union { __hip_bfloat162 h; u32 u; } v;
    v.h = __float22bfloat162_rn(make_float2(a, b));
    return v.u;
}
// exact fp32 rerank, R2's accepted expression tree (sequential fmaf over 64 float4s)
__device__ __forceinline__ void exact_rerank(const float* __restrict__ X,
                                             const float* __restrict__ CB,
                                             const float* __restrict__ xx,
                                             const float* __restrict__ cbn,
                                             int row, int col,
                                             u64* __restrict__ best) {
    const float4* xp = (const float4*)(X + (size_t)row * COLS);
    const float4* cp = (const float4*)(CB + (size_t)col * COLS);
    float d = 0.f;
    #pragma unroll 8
    for (int q = 0; q < 64; ++q) {
        float4 a = xp[q], b = cp[q];
        d = fmaf(a.x, b.x, d); d = fmaf(a.y, b.y, d);
        d = fmaf(a.z, b.z, d); d = fmaf(a.w, b.w, d);
    }
    float d2e = fmaf(-2.f, d, xx[row]) + cbn[col];
    u64 pk = ((u64)f32_sortable(d2e) << 32) | (u32)col;
    atomicMin(&best[row], pk);
}

// ---------- kernel 0: xx[r], X->bf16, init best/cbn_max ----------
__global__ __launch_bounds__(256) void k_prep(const float* __restrict__ X,
                                              short* __restrict__ Xh,
                                              float* __restrict__ xx,
                                              u64* __restrict__ best,
                                              u32* __restrict__ cbn_max) {
    int r    = blockIdx.x * 4 + (threadIdx.x >> 6);
    int lane = threadIdx.x & 63;
    float4 v = *reinterpret_cast<const float4*>(X + (size_t)r * COLS + lane * 4);
    uint2 p; p.x = pk2(v.x, v.y); p.y = pk2(v.z, v.w);
    *reinterpret_cast<uint2*>(Xh + (size_t)r * COLS + lane * 4) = p;
    float s = wave_sum(v.x*v.x + v.y*v.y + v.z*v.z + v.w*v.w);
    if (lane == 0) { xx[r] = s; best[r] = ~0ull; }
    if (blockIdx.x == 0 && threadIdx.x == 0) *cbn_max = 0u;
}

// ---------- kernel 1: codebook (fp32 + bf16) + |cb|^2 + max|cb|^2 ----------
__global__ __launch_bounds__(256) void k_codebook(const float* __restrict__ fc,
                                                  const float* __restrict__ Wi,
                                                  const float* __restrict__ Wo,
                                                  float* __restrict__ CB,
                                                  short* __restrict__ CBh,
                                                  float* __restrict__ cbn,
                                                  u32* __restrict__ cbn_max) {
    int n = blockIdx.x, tid = threadIdx.x;
    int o = tid >> 4, k = tid & 15;
    __shared__ float fcs[256], wis[256], wos[256], hs[256], sq[256];
    fcs[tid] = fc[(size_t)n * 256 + tid];
    wis[tid] = Wi[tid];
    wos[tid] = Wo[tid];
    __syncthreads();
    float hp = 0.f;
    #pragma unroll
    for (int i = 0; i < 16; ++i) hp = fmaf(wis[o*16 + i], fcs[i*16 + k], hp);
    hs[tid] = hp;
    __syncthreads();
    float h0 = hs[o * 16];
    float x3 = h0 * h0 * h0;
    float inner = 0.7978845608028654f * fmaf(0.044715f, x3, h0);
    float g = 0.5f * h0 * (1.f + tanhf(inner));
    float hg = hp * g;
    __syncthreads();
    hs[tid] = hg;
    __syncthreads();
    float cv = 0.f;
    #pragma unroll
    for (int i = 0; i < 16; ++i) cv = fmaf(wos[o*16 + i], hs[i*16 + k], cv);
    CB[(size_t)n * 256 + tid] = cv;
    { union { __hip_bfloat16 h; short s; } c; c.h = __float2bfloat16(cv);
      CBh[(size_t)n * 256 + tid] = c.s; }
    sq[tid] = cv * cv;
    __syncthreads();
    #pragma unroll
    for (int st = 128; st > 0; st >>= 1) {
        if (tid < st) sq[tid] += sq[tid + st];
        __syncthreads();
    }
    if (tid == 0) { cbn[n] = sq[0]; atomicMax(cbn_max, __float_as_uint(sq[0])); }
}

// ---------- kernel 2: FUSED tall-block screen, T3/T4 counted-vmcnt pipeline ----------
// 512 blocks x 512 threads (8 waves x 16 rows). Block owns 128 rows x all 4096
// codes; 2 sweeps (min-scan, then candidate-collect). B streamed as 256 16KB
// slices through a TRIPLE LDS buffer. Per step (two-barrier discipline):
//   s_waitcnt vmcnt(4)  -> slice t landed (slices t+1,t+2 still in flight)
//   s_barrier (A)       -> all waves agree buf ready
//   ds_read frags + 16 MFMA (+ reg-only epilogue at kb==3)
//   s_barrier (B)       -> all waves done reading buf
//   stage slice t+3 into the just-freed buffer (vmcnt never drains to 0)
// Wraparound staging keeps outstanding-count uniform so constant vmcnt(4) is
// exact. cbn lives in LDS (lgkm-counted; a vmem read here would FIFO-drain
// the staged loads). Candidates buffered in 6 static reg slots (rule #20),
// exact fp32 rerank AFTER the loop; >6/lane overflow falls back inline.
__global__ __launch_bounds__(512, 4) void k_screen_fused(
        const short* __restrict__ Xh,
        const short* __restrict__ CBh,
        const float* __restrict__ X,
        const float* __restrict__ CB,
        const float* __restrict__ cbn,
        const float* __restrict__ xx,
        u64* __restrict__ best,
        const u32* __restrict__ cbn_max) {
    __shared__ __align__(16) short Bs[3][128 * 64];   // 48 KB
    __shared__ float cbn_s[Nn];                       // 16 KB

    const int tid  = threadIdx.x;
    const int lane = tid & 63;
    const int w    = tid >> 6;          // wave 0..7
    const int bmBase = blockIdx.x * 128;

    const int srow   = lane >> 3;       // 0..7 within 8-row group
    const int schunk = lane & 7;
    const int gc     = schunk ^ srow;   // inverse-swizzled global chunk

#define STAGE(slice, buf) do { \
        int _s = (slice); \
        int _bn = _s >> 2, _kb = _s & 3; \
        _Pragma("unroll") \
        for (int _i = 0; _i < 2; ++_i) { \
            int _g8 = (w * 2 + _i) * 8; \
            const short* _gb = CBh + ((size_t)(_bn * 128 + _g8 + srow) << 8) \
                             + _kb * 64 + gc * 8; \
            GLOAD_LDS(_gb, &Bs[(buf)][_g8 * 64]); \
        } \
    } while (0)

    // cbn -> LDS (all 4096 codes), 8 floats per thread
    {
        float4 c0 = *reinterpret_cast<const float4*>(&cbn[tid * 8]);
        float4 c1 = *reinterpret_cast<const float4*>(&cbn[tid * 8 + 4]);
        *reinterpret_cast<float4*>(&cbn_s[tid * 8])     = c0;
        *reinterpret_cast<float4*>(&cbn_s[tid * 8 + 4]) = c1;
    }

    // A fragments: wave w owns rows bmBase + w*16 .. +15
    bf16x8 af[8];
    {
        int arow = bmBase + w * 16 + (lane & 15);
        const short* ap = Xh + ((size_t)arow << 8) + (lane >> 4) * 8;
        #pragma unroll
        for (int kc = 0; kc < 8; ++kc)
            af[kc] = *reinterpret_cast<const bf16x8*>(ap + kc * 32);
    }
    float xxv[4];
    #pragma unroll
    for (int rg = 0; rg < 4; ++rg)
        xxv[rg] = xx[bmBase + w * 16 + (lane >> 4) * 4 + rg];
    const float cmax = __uint_as_float(*cbn_max);

    __syncthreads();            // cbn_s visible to all waves (full drain, prologue only)

    // prologue: stage slices 0,1,2 (6 loads/wave outstanding)
    STAGE(0, 0); STAGE(1, 1); STAGE(2, 2);

    f32x4 acc[8];
    float rmin[4] = {1e30f, 1e30f, 1e30f, 1e30f};
    float thr[4]  = {1e30f, 1e30f, 1e30f, 1e30f};
    u32 c0 = 0, c1 = 0, c2 = 0, c3 = 0, c4 = 0, c5 = 0;
    int ccnt = 0;
    int p = 0;                  // LDS buffer cursor (= step mod 3)

    for (int t4 = 0; t4 < 64; ++t4) {       // 2 sweeps x 32 bn-tiles
        const int bn = t4 & 31;
        #pragma unroll
        for (int kb = 0; kb < 4; ++kb) {
            asm volatile("s_waitcnt vmcnt(4)" ::: "memory");
            __builtin_amdgcn_sched_barrier(0);
            __builtin_amdgcn_s_barrier();               // (A) buf[p] ready
            __builtin_amdgcn_sched_barrier(0);

            if (kb == 0) {
                #pragma unroll
                for (int ni = 0; ni < 8; ++ni) acc[ni] = f32x4{0.f, 0.f, 0.f, 0.f};
            }
            const short* Bcur = &Bs[p][0];
            #pragma unroll
            for (int ks = 0; ks < 2; ++ks) {
                bf16x8 bfv[8];
                int kgl = ks * 4 + (lane >> 4);
                #pragma unroll
                for (int ni = 0; ni < 8; ++ni) {
                    int row = ni * 16 + (lane & 15);
                    bfv[ni] = *reinterpret_cast<const bf16x8*>(
                        &Bcur[row * 64 + ((kgl ^ (row & 7)) << 3)]);
                }
                #pragma unroll
                for (int ni = 0; ni < 8; ++ni)
                    acc[ni] = __builtin_amdgcn_mfma_f32_16x16x32_bf16(
                        af[kb * 2 + ks], bfv[ni], acc[ni], 0, 0, 0);
            }

            if (kb == 3) {      // per-bn epilogue: regs + LDS(cbn_s) only
                float cb_v[8];
                #pragma unroll
                for (int ni = 0; ni < 8; ++ni)
                    cb_v[ni] = cbn_s[bn * 128 + ni * 16 + (lane & 15)];
                if (t4 < 32) {
                    // sweep 1: per-row running min
                    #pragma unroll
                    for (int rg = 0; rg < 4; ++rg) {
                        float m = 1e30f;
                        #pragma unroll
                        for (int ni = 0; ni < 8; ++ni) {
                            float d2a = fmaf(-2.f, acc[ni][rg], xxv[rg]) + cb_v[ni];
                            m = fminf(m, d2a);
                        }
                        #pragma unroll
                        for (int d = 1; d < 16; d <<= 1)
                            m = fminf(m, __shfl_xor(m, d, 64));
                        rmin[rg] = fminf(rmin[rg], m);
                    }
                    if (t4 == 31) {
                        #pragma unroll
                        for (int rg = 0; rg < 4; ++rg)
                            thr[rg] = rmin[rg] + fmaf(0.003f, sqrtf(xxv[rg] * cmax), 0.01f);
                    }
                } else {
                    // sweep 2: collect candidates into static reg slots
                    #pragma unroll
                    for (int rg = 0; rg < 4; ++rg) {
                        #pragma unroll
                        for (int ni = 0; ni < 8; ++ni) {
                            float d2a = fmaf(-2.f, acc[ni][rg], xxv[rg]) + cb_v[ni];
                            if (d2a <= thr[rg]) {
                                u32 enc = ((u32)rg << 16) | (u32)(bn * 128 + ni * 16 + (lane & 15));
                                if      (ccnt == 0) c0 = enc;
                                else if (ccnt == 1) c1 = enc;
                                else if (ccnt == 2) c2 = enc;
                                else if (ccnt == 3) c3 = enc;
                                else if (ccnt == 4) c4 = enc;
                                else if (ccnt == 5) c5 = enc;
                                else {  // ~impossible overflow: inline exact (drains, correct)
                                    exact_rerank(X, CB, xx, cbn,
                                        bmBase + w * 16 + (lane >> 4) * 4 + rg,
                                        bn * 128 + ni * 16 + (lane & 15), best);
                                }
                                ++ccnt;
                            }
                        }
                    }
                }
            }

            __builtin_amdgcn_sched_barrier(0);
            __builtin_amdgcn_s_barrier();               // (B) buf[p] free
            __builtin_amdgcn_sched_barrier(0);
            // stage slice t+3 into just-freed buffer (wrap keeps vmcnt uniform)
            STAGE((t4 * 4 + kb + 3) & 127, p);
            p = (p == 2) ? 0 : p + 1;
        }
    }

    // post-loop: exact fp32 rerank of buffered candidates (R2's tree)
    const int rowBase = bmBase + w * 16 + (lane >> 4) * 4;
    if (ccnt > 0) exact_rerank(X, CB, xx, cbn, rowBase + (int)(c0 >> 16), (int)(c0 & 0xFFFF), best);
    if (ccnt > 1) exact_rerank(X, CB, xx, cbn, rowBase + (int)(c1 >> 16), (int)(c1 & 0xFFFF), best);
    if (ccnt > 2) exact_rerank(X, CB, xx, cbn, rowBase + (int)(c2 >> 16), (int)(c2 & 0xFFFF), best);
    if (ccnt > 3) exact_rerank(X, CB, xx, cbn, rowBase + (int)(c3 >> 16), (int)(c3 & 0xFFFF), best);
    if (ccnt > 4) exact_rerank(X, CB, xx, cbn, rowBase + (int)(c4 >> 16), (int)(c4 & 0xFFFF), best);
    if (ccnt > 5) exact_rerank(X, CB, xx, cbn, rowBase + (int)(c5 >> 16), (int)(c5 & 0xFFFF), best);
#undef STAGE
}

// ---------- kernel 3: gather e, Householder STE ----------
__global__ __launch_bounds__(256) void k_epilogue(const float* __restrict__ X,
                                                  const float* __restrict__ CB,
                                                  const u64* __restrict__ best,
                                                  float* __restrict__ Eout,
                                                  float* __restrict__ Sout) {
    int r    = blockIdx.x * 4 + (threadIdx.x >> 6);
    int lane = threadIdx.x & 63;
    int idx  = (int)(best[r] & 0xffffffffull);

    float4 xv = *reinterpret_cast<const float4*>(X  + (size_t)r   * COLS + lane * 4);
    float4 ev = *reinterpret_cast<const float4*>(CB + (size_t)idx * COLS + lane * 4);

    float xn2 = wave_sum(dot4(xv, xv));
    float en2 = wave_sum(dot4(ev, ev));
    float xn = sqrtf(xn2), en = sqrtf(en2);
    float invx = 1.f / fmaxf(xn, EPSF);
    float inve = 1.f / fmaxf(en, EPSF);

    float4 xd, ed, sd0;
    xd.x = xv.x*invx; xd.y = xv.y*invx; xd.z = xv.z*invx; xd.w = xv.w*invx;
    ed.x = ev.x*inve; ed.y = ev.y*inve; ed.z = ev.z*inve; ed.w = ev.w*inve;
    sd0.x = xd.x+ed.x; sd0.y = xd.y+ed.y; sd0.z = xd.z+ed.z; sd0.w = xd.w+ed.w;

    float sdn2 = wave_sum(dot4(sd0, sd0));
    float p1   = wave_sum(dot4(sd0, xv));
    float p2   = wave_sum(dot4(xd,  xv));
    float invs = 1.f / fmaxf(sqrtf(sdn2), EPSF);

    float csd = -2.f * invs * invs * p1;
    float ced =  2.f * p2;
    float4 rr;
    rr.x = fmaf(csd, sd0.x, fmaf(ced, ed.x, xv.x));
    rr.y = fmaf(csd, sd0.y, fmaf(ced, ed.y, xv.y));
    rr.z = fmaf(csd, sd0.z, fmaf(ced, ed.z, xv.z));
    rr.w = fmaf(csd, sd0.w, fmaf(ced, ed.w, xv.w));
    float sc = en * invx;
    float4 sv; sv.x = rr.x*sc; sv.y = rr.y*sc; sv.z = rr.z*sc; sv.w = rr.w*sc;

    *reinterpret_cast<float4*>(Eout + (size_t)r * COLS + lane * 4) = ev;
    *reinterpret_cast<float4*>(Sout + (size_t)r * COLS + lane * 4) = sv;
}

// ---------- launcher ----------
extern "C" void kernel_launch(void* const* d_in, const int* in_sizes, int n_in,
                              void* d_out, int out_size, void* d_ws, size_t ws_size,
                              hipStream_t stream) {
    const float* x  = (const float*)d_in[0];
    const float* fc = (const float*)d_in[1];
    const float* Wi = (const float*)d_in[2];
    const float* Wo = (const float*)d_in[3];

    // ws layout (~5 MB)
    char* ws = (char*)d_ws;
    u64*   best    = (u64*)ws;                            ws += (size_t)ROWS * 8;
    float* CBws    = (float*)ws;                          ws += (size_t)Nn * COLS * 4;
    float* cbn     = (float*)ws;                          ws += (size_t)Nn * 4;
    float* xx      = (float*)ws;                          ws += (size_t)ROWS * 4;
    u32*   cbn_max = (u32*)ws;

    // bf16 copies live in d_out (128 MiB), only overwritten by k_epilogue at
    // the very end: Xh = 32 MiB at offset 0, CBh = 2 MiB at offset 64 MiB.
    short* Xh  = (short*)d_out;
    short* CBh = (short*)((char*)d_out + (64u << 20));

    float* Eout = (float*)d_out;
    float* Sout = Eout + (size_t)ROWS * COLS;

    k_prep<<<ROWS / 4, 256, 0, stream>>>(x, Xh, xx, best, cbn_max);
    k_codebook<<<Nn, 256, 0, stream>>>(fc, Wi, Wo, CBws, CBh, cbn, cbn_max);
    k_screen_fused<<<ROWS / 128, 512, 0, stream>>>(Xh, CBh, x, CBws, cbn, xx, best, cbn_max);
    k_epilogue<<<ROWS / 4, 256, 0, stream>>>(x, CBws, best, Eout, Sout);
}

// Round 7
// 560.038 us; speedup vs baseline: 1.7395x; 1.7395x over previous
//
#include <hip/hip_runtime.h>
#include <hip/hip_bf16.h>
#include <stdint.h>

// Problem dims (fixed by reference)
#define Bq    8192
#define Hh    8
#define Dd    16
#define Kk    16
#define Nn    4096
#define DFf   16
#define ROWS  (Bq*Hh)          // 65536
#define COLS  (Dd*Kk)          // 256
#define EPSF  1e-6f

typedef unsigned long long u64;
typedef unsigned int u32;
typedef __attribute__((ext_vector_type(8))) short bf16x8;
typedef __attribute__((ext_vector_type(4))) float f32x4;

// async global->LDS, 16B per lane; LDS dest = wave-uniform base + lane*16
#define GLOAD_LDS(g, l) __builtin_amdgcn_global_load_lds( \
    (const __attribute__((address_space(1))) u32*)(g), \
    (__attribute__((address_space(3))) u32*)(l), 16, 0, 0)

// ---------- helpers ----------
__device__ __forceinline__ float dot4(float4 a, float4 b) {
    return fmaf(a.x, b.x, fmaf(a.y, b.y, fmaf(a.z, b.z, a.w * b.w)));
}
__device__ __forceinline__ float wave_sum(float v) {
    #pragma unroll
    for (int m = 32; m > 0; m >>= 1) v += __shfl_xor(v, m, 64);
    return v;
}
__device__ __forceinline__ u32 f32_sortable(float f) {
    u32 u = __float_as_uint(f);
    return (u & 0x80000000u) ? ~u : (u | 0x80000000u);
}
// pack 2 floats -> 2 bf16 (RNE); low 16 bits = a
__device__ __forceinline__ u32 pk2(float a, float b) {
    union { __hip_bfloat162 h; u32 u; } v;
    v.h = __float22bfloat162_rn(make_float2(a, b));
    return v.u;
}
// exact fp32 rerank, R2's accepted expression tree (sequential fmaf over 64 float4s)
__device__ __forceinline__ void exact_rerank(const float* __restrict__ X,
                                             const float* __restrict__ CB,
                                             const float* __restrict__ xx,
                                             const float* __restrict__ cbn,
                                             int row, int col,
                                             u64* __restrict__ best) {
    const float4* xp = (const float4*)(X + (size_t)row * COLS);
    const float4* cp = (const float4*)(CB + (size_t)col * COLS);
    float d = 0.f;
    #pragma unroll 8
    for (int q = 0; q < 64; ++q) {
        float4 a = xp[q], b = cp[q];
        d = fmaf(a.x, b.x, d); d = fmaf(a.y, b.y, d);
        d = fmaf(a.z, b.z, d); d = fmaf(a.w, b.w, d);
    }
    float d2e = fmaf(-2.f, d, xx[row]) + cbn[col];
    u64 pk = ((u64)f32_sortable(d2e) << 32) | (u32)col;
    atomicMin(&best[row], pk);
}

// ---------- kernel 0: xx[r], X->bf16, init best/cbn_max ----------
__global__ __launch_bounds__(256) void k_prep(const float* __restrict__ X,
                                              short* __restrict__ Xh,
                                              float* __restrict__ xx,
                                              u64* __restrict__ best,
                                              u32* __restrict__ cbn_max) {
    int r    = blockIdx.x * 4 + (threadIdx.x >> 6);
    int lane = threadIdx.x & 63;
    float4 v = *reinterpret_cast<const float4*>(X + (size_t)r * COLS + lane * 4);
    uint2 p; p.x = pk2(v.x, v.y); p.y = pk2(v.z, v.w);
    *reinterpret_cast<uint2*>(Xh + (size_t)r * COLS + lane * 4) = p;
    float s = wave_sum(v.x*v.x + v.y*v.y + v.z*v.z + v.w*v.w);
    if (lane == 0) { xx[r] = s; best[r] = ~0ull; }
    if (blockIdx.x == 0 && threadIdx.x == 0) *cbn_max = 0u;
}

// ---------- kernel 1: codebook (fp32 + bf16) + |cb|^2 + max|cb|^2 ----------
__global__ __launch_bounds__(256) void k_codebook(const float* __restrict__ fc,
                                                  const float* __restrict__ Wi,
                                                  const float* __restrict__ Wo,
                                                  float* __restrict__ CB,
                                                  short* __restrict__ CBh,
                                                  float* __restrict__ cbn,
                                                  u32* __restrict__ cbn_max) {
    int n = blockIdx.x, tid = threadIdx.x;
    int o = tid >> 4, k = tid & 15;
    __shared__ float fcs[256], wis[256], wos[256], hs[256], sq[256];
    fcs[tid] = fc[(size_t)n * 256 + tid];
    wis[tid] = Wi[tid];
    wos[tid] = Wo[tid];
    __syncthreads();
    float hp = 0.f;
    #pragma unroll
    for (int i = 0; i < 16; ++i) hp = fmaf(wis[o*16 + i], fcs[i*16 + k], hp);
    hs[tid] = hp;
    __syncthreads();
    float h0 = hs[o * 16];
    float x3 = h0 * h0 * h0;
    float inner = 0.7978845608028654f * fmaf(0.044715f, x3, h0);
    float g = 0.5f * h0 * (1.f + tanhf(inner));
    float hg = hp * g;
    __syncthreads();
    hs[tid] = hg;
    __syncthreads();
    float cv = 0.f;
    #pragma unroll
    for (int i = 0; i < 16; ++i) cv = fmaf(wos[o*16 + i], hs[i*16 + k], cv);
    CB[(size_t)n * 256 + tid] = cv;
    { union { __hip_bfloat16 h; short s; } c; c.h = __float2bfloat16(cv);
      CBh[(size_t)n * 256 + tid] = c.s; }
    sq[tid] = cv * cv;
    __syncthreads();
    #pragma unroll
    for (int st = 128; st > 0; st >>= 1) {
        if (tid < st) sq[tid] += sq[tid + st];
        __syncthreads();
    }
    if (tid == 0) { cbn[n] = sq[0]; atomicMax(cbn_max, __float_as_uint(sq[0])); }
}

// ---------- kernel 2: SINGLE-SWEEP tall-block screen, counted-vmcnt pipeline ----------
// 1024 blocks x 256 threads (4 waves x 16 rows = 64 rows/block), all 4096
// codes streamed ONCE as 128 16KB slices (128 codes x 64 K) through a triple
// LDS buffer. Per step:
//   s_waitcnt vmcnt(8) -> slice t landed (t+1,t+2 in flight, 4 issues/wave each)
//   s_barrier (A); ds_read frags + 16 MFMA; at kb==3: running-min update +
//   candidate collect vs thr = rmin + delta (running-min collection is safe:
//   d2a(c*) <= m_run + 2*err <= m_run + delta, so the true argmin and all
//   exact ties always enter the candidate set);
//   s_barrier (B); STAGE slice t+3 into the freed buffer (vmcnt never 0).
// cbn lives in LDS (lgkm-counted). Candidates -> 8 static reg slots
// (rule #20), exact fp32 rerank AFTER the loop; overflow falls back inline.
// __launch_bounds__(256,2): 256-VGPR cap -> no spill (R6's failure mode);
// LDS 64KB -> 2 blocks/CU.
__global__ __launch_bounds__(256, 2) void k_screen_fused(
        const short* __restrict__ Xh,
        const short* __restrict__ CBh,
        const float* __restrict__ X,
        const float* __restrict__ CB,
        const float* __restrict__ cbn,
        const float* __restrict__ xx,
        u64* __restrict__ best,
        const u32* __restrict__ cbn_max) {
    __shared__ __align__(16) short Bs[3][128 * 64];   // 48 KB
    __shared__ float cbn_s[Nn];                       // 16 KB

    const int tid  = threadIdx.x;
    const int lane = tid & 63;
    const int w    = tid >> 6;          // wave 0..3
    const int bmBase = blockIdx.x * 64;

    const int srow   = lane >> 3;       // 0..7 within 8-row group
    const int schunk = lane & 7;
    const int gc     = schunk ^ srow;   // inverse-swizzled global chunk

#define STAGE(slice, buf) do { \
        int _s = (slice); \
        int _bn = _s >> 2, _kb = _s & 3; \
        _Pragma("unroll") \
        for (int _i = 0; _i < 4; ++_i) { \
            int _g8 = w * 32 + _i * 8; \
            const short* _gb = CBh + ((size_t)(_bn * 128 + _g8 + srow) << 8) \
                             + _kb * 64 + gc * 8; \
            GLOAD_LDS(_gb, &Bs[(buf)][_g8 * 64]); \
        } \
    } while (0)

    // cbn -> LDS (all 4096 codes), 16 floats per thread
    #pragma unroll
    for (int j = 0; j < 4; ++j)
        *reinterpret_cast<float4*>(&cbn_s[tid * 16 + j * 4]) =
            *reinterpret_cast<const float4*>(&cbn[tid * 16 + j * 4]);

    // A fragments: wave w owns rows bmBase + w*16 .. +15
    bf16x8 af[8];
    {
        int arow = bmBase + w * 16 + (lane & 15);
        const short* ap = Xh + ((size_t)arow << 8) + (lane >> 4) * 8;
        #pragma unroll
        for (int kc = 0; kc < 8; ++kc)
            af[kc] = *reinterpret_cast<const bf16x8*>(ap + kc * 32);
    }
    float xxv[4];
    #pragma unroll
    for (int rg = 0; rg < 4; ++rg)
        xxv[rg] = xx[bmBase + w * 16 + (lane >> 4) * 4 + rg];
    const float cmax = __uint_as_float(*cbn_max);
    float dlt[4];
    #pragma unroll
    for (int rg = 0; rg < 4; ++rg)
        dlt[rg] = fmaf(0.003f, sqrtf(xxv[rg] * cmax), 0.01f);

    __syncthreads();            // full drain (prologue only): vmcnt back to 0

    // prologue: stage slices 0,1,2 (12 loads/wave outstanding)
    STAGE(0, 0); STAGE(1, 1); STAGE(2, 2);

    f32x4 acc[8];
    float rmin[4] = {1e30f, 1e30f, 1e30f, 1e30f};
    u32 c0 = 0, c1 = 0, c2 = 0, c3 = 0, c4 = 0, c5 = 0, c6 = 0, c7 = 0;
    int ccnt = 0;
    int p = 0;                  // LDS buffer cursor (= step mod 3)

    for (int t4 = 0; t4 < 32; ++t4) {       // single sweep over 32 bn-tiles
        const int bn = t4;
        #pragma unroll
        for (int kb = 0; kb < 4; ++kb) {
            asm volatile("s_waitcnt vmcnt(8)" ::: "memory");
            __builtin_amdgcn_sched_barrier(0);
            __builtin_amdgcn_s_barrier();               // (A) buf[p] ready
            __builtin_amdgcn_sched_barrier(0);

            if (kb == 0) {
                #pragma unroll
                for (int ni = 0; ni < 8; ++ni) acc[ni] = f32x4{0.f, 0.f, 0.f, 0.f};
            }
            const short* Bcur = &Bs[p][0];
            #pragma unroll
            for (int ks = 0; ks < 2; ++ks) {
                bf16x8 bfv[8];
                int kgl = ks * 4 + (lane >> 4);
                #pragma unroll
                for (int ni = 0; ni < 8; ++ni) {
                    int row = ni * 16 + (lane & 15);
                    bfv[ni] = *reinterpret_cast<const bf16x8*>(
                        &Bcur[row * 64 + ((kgl ^ (row & 7)) << 3)]);
                }
                #pragma unroll
                for (int ni = 0; ni < 8; ++ni)
                    acc[ni] = __builtin_amdgcn_mfma_f32_16x16x32_bf16(
                        af[kb * 2 + ks], bfv[ni], acc[ni], 0, 0, 0);
            }

            if (kb == 3) {      // per-bn epilogue: regs + LDS(cbn_s) only
                float cb_v[8];
                #pragma unroll
                for (int ni = 0; ni < 8; ++ni)
                    cb_v[ni] = cbn_s[bn * 128 + ni * 16 + (lane & 15)];
                float d2s[4][8];
                #pragma unroll
                for (int rg = 0; rg < 4; ++rg) {
                    float m = 1e30f;
                    #pragma unroll
                    for (int ni = 0; ni < 8; ++ni) {
                        d2s[rg][ni] = fmaf(-2.f, acc[ni][rg], xxv[rg]) + cb_v[ni];
                        m = fminf(m, d2s[rg][ni]);
                    }
                    #pragma unroll
                    for (int d = 1; d < 16; d <<= 1)
                        m = fminf(m, __shfl_xor(m, d, 64));
                    rmin[rg] = fminf(rmin[rg], m);   // running min incl. this tile
                }
                #pragma unroll
                for (int rg = 0; rg < 4; ++rg) {
                    float thr = rmin[rg] + dlt[rg];
                    #pragma unroll
                    for (int ni = 0; ni < 8; ++ni) {
                        if (d2s[rg][ni] <= thr) {
                            u32 enc = ((u32)rg << 16) | (u32)(bn * 128 + ni * 16 + (lane & 15));
                            if      (ccnt == 0) c0 = enc;
                            else if (ccnt == 1) c1 = enc;
                            else if (ccnt == 2) c2 = enc;
                            else if (ccnt == 3) c3 = enc;
                            else if (ccnt == 4) c4 = enc;
                            else if (ccnt == 5) c5 = enc;
                            else if (ccnt == 6) c6 = enc;
                            else if (ccnt == 7) c7 = enc;
                            else {  // rare overflow: inline exact (stalls, correct)
                                exact_rerank(X, CB, xx, cbn,
                                    bmBase + w * 16 + (lane >> 4) * 4 + rg,
                                    bn * 128 + ni * 16 + (lane & 15), best);
                            }
                            ++ccnt;
                        }
                    }
                }
            }

            __builtin_amdgcn_sched_barrier(0);
            __builtin_amdgcn_s_barrier();               // (B) buf[p] free
            __builtin_amdgcn_sched_barrier(0);
            // stage slice t+3 into just-freed buffer (wrap keeps vmcnt uniform)
            STAGE((t4 * 4 + kb + 3) & 127, p);
            p = (p == 2) ? 0 : p + 1;
        }
    }

    // post-loop: exact fp32 rerank of buffered candidates (R2's tree)
    const int rowBase = bmBase + w * 16 + (lane >> 4) * 4;
    if (ccnt > 0) exact_rerank(X, CB, xx, cbn, rowBase + (int)(c0 >> 16), (int)(c0 & 0xFFFF), best);
    if (ccnt > 1) exact_rerank(X, CB, xx, cbn, rowBase + (int)(c1 >> 16), (int)(c1 & 0xFFFF), best);
    if (ccnt > 2) exact_rerank(X, CB, xx, cbn, rowBase + (int)(c2 >> 16), (int)(c2 & 0xFFFF), best);
    if (ccnt > 3) exact_rerank(X, CB, xx, cbn, rowBase + (int)(c3 >> 16), (int)(c3 & 0xFFFF), best);
    if (ccnt > 4) exact_rerank(X, CB, xx, cbn, rowBase + (int)(c4 >> 16), (int)(c4 & 0xFFFF), best);
    if (ccnt > 5) exact_rerank(X, CB, xx, cbn, rowBase + (int)(c5 >> 16), (int)(c5 & 0xFFFF), best);
    if (ccnt > 6) exact_rerank(X, CB, xx, cbn, rowBase + (int)(c6 >> 16), (int)(c6 & 0xFFFF), best);
    if (ccnt > 7) exact_rerank(X, CB, xx, cbn, rowBase + (int)(c7 >> 16), (int)(c7 & 0xFFFF), best);
#undef STAGE
}

// ---------- kernel 3: gather e, Householder STE ----------
__global__ __launch_bounds__(256) void k_epilogue(const float* __restrict__ X,
                                                  const float* __restrict__ CB,
                                                  const u64* __restrict__ best,
                                                  float* __restrict__ Eout,
                                                  float* __restrict__ Sout) {
    int r    = blockIdx.x * 4 + (threadIdx.x >> 6);
    int lane = threadIdx.x & 63;
    int idx  = (int)(best[r] & 0xffffffffull);

    float4 xv = *reinterpret_cast<const float4*>(X  + (size_t)r   * COLS + lane * 4);
    float4 ev = *reinterpret_cast<const float4*>(CB + (size_t)idx * COLS + lane * 4);

    float xn2 = wave_sum(dot4(xv, xv));
    float en2 = wave_sum(dot4(ev, ev));
    float xn = sqrtf(xn2), en = sqrtf(en2);
    float invx = 1.f / fmaxf(xn, EPSF);
    float inve = 1.f / fmaxf(en, EPSF);

    float4 xd, ed, sd0;
    xd.x = xv.x*invx; xd.y = xv.y*invx; xd.z = xv.z*invx; xd.w = xv.w*invx;
    ed.x = ev.x*inve; ed.y = ev.y*inve; ed.z = ev.z*inve; ed.w = ev.w*inve;
    sd0.x = xd.x+ed.x; sd0.y = xd.y+ed.y; sd0.z = xd.z+ed.z; sd0.w = xd.w+ed.w;

    float sdn2 = wave_sum(dot4(sd0, sd0));
    float p1   = wave_sum(dot4(sd0, xv));
    float p2   = wave_sum(dot4(xd,  xv));
    float invs = 1.f / fmaxf(sqrtf(sdn2), EPSF);

    float csd = -2.f * invs * invs * p1;
    float ced =  2.f * p2;
    float4 rr;
    rr.x = fmaf(csd, sd0.x, fmaf(ced, ed.x, xv.x));
    rr.y = fmaf(csd, sd0.y, fmaf(ced, ed.y, xv.y));
    rr.z = fmaf(csd, sd0.z, fmaf(ced, ed.z, xv.z));
    rr.w = fmaf(csd, sd0.w, fmaf(ced, ed.w, xv.w));
    float sc = en * invx;
    float4 sv; sv.x = rr.x*sc; sv.y = rr.y*sc; sv.z = rr.z*sc; sv.w = rr.w*sc;

    *reinterpret_cast<float4*>(Eout + (size_t)r * COLS + lane * 4) = ev;
    *reinterpret_cast<float4*>(Sout + (size_t)r * COLS + lane * 4) = sv;
}

// ---------- launcher ----------
extern "C" void kernel_launch(void* const* d_in, const int* in_sizes, int n_in,
                              void* d_out, int out_size, void* d_ws, size_t ws_size,
                              hipStream_t stream) {
    const float* x  = (const float*)d_in[0];
    const float* fc = (const float*)d_in[1];
    const float* Wi = (const float*)d_in[2];
    const float* Wo = (const float*)d_in[3];

    // ws layout (~5 MB)
    char* ws = (char*)d_ws;
    u64*   best    = (u64*)ws;                            ws += (size_t)ROWS * 8;
    float* CBws    = (float*)ws;                          ws += (size_t)Nn * COLS * 4;
    float* cbn     = (float*)ws;                          ws += (size_t)Nn * 4;
    float* xx      = (float*)ws;                          ws += (size_t)ROWS * 4;
    u32*   cbn_max = (u32*)ws;

    // bf16 copies live in d_out (128 MiB), only overwritten by k_epilogue at
    // the very end: Xh = 32 MiB at offset 0, CBh = 2 MiB at offset 64 MiB.
    short* Xh  = (short*)d_out;
    short* CBh = (short*)((char*)d_out + (64u << 20));

    float* Eout = (float*)d_out;
    float* Sout = Eout + (size_t)ROWS * COLS;

    k_prep<<<ROWS / 4, 256, 0, stream>>>(x, Xh, xx, best, cbn_max);
    k_codebook<<<Nn, 256, 0, stream>>>(fc, Wi, Wo, CBws, CBh, cbn, cbn_max);
    k_screen_fused<<<ROWS / 64, 256, 0, stream>>>(Xh, CBh, x, CBws, cbn, xx, best, cbn_max);
    k_epilogue<<<ROWS / 4, 256, 0, stream>>>(x, CBws, best, Eout, Sout);
}

// Round 8
// 513.612 us; speedup vs baseline: 1.8968x; 1.0904x over previous
//
#include <hip/hip_runtime.h>
#include <hip/hip_bf16.h>
#include <stdint.h>

// Problem dims (fixed by reference)
#define Bq    8192
#define Hh    8
#define Dd    16
#define Kk    16
#define Nn    4096
#define DFf   16
#define ROWS  (Bq*Hh)          // 65536
#define COLS  (Dd*Kk)          // 256
#define EPSF  1e-6f

typedef unsigned long long u64;
typedef unsigned int u32;
typedef __attribute__((ext_vector_type(8))) short bf16x8;
typedef __attribute__((ext_vector_type(4))) float f32x4;

// ---------- helpers ----------
__device__ __forceinline__ float dot4(float4 a, float4 b) {
    return fmaf(a.x, b.x, fmaf(a.y, b.y, fmaf(a.z, b.z, a.w * b.w)));
}
__device__ __forceinline__ float wave_sum(float v) {
    #pragma unroll
    for (int m = 32; m > 0; m >>= 1) v += __shfl_xor(v, m, 64);
    return v;
}
__device__ __forceinline__ u32 f32_sortable(float f) {
    u32 u = __float_as_uint(f);
    return (u & 0x80000000u) ? ~u : (u | 0x80000000u);
}
// pack 2 floats -> 2 bf16 (RNE); low 16 bits = a
__device__ __forceinline__ u32 pk2(float a, float b) {
    union { __hip_bfloat162 h; u32 u; } v;
    v.h = __float22bfloat162_rn(make_float2(a, b));
    return v.u;
}
// exact fp32 rerank, R2's accepted expression tree (sequential fmaf over 64 float4s)
__device__ __forceinline__ void exact_rerank(const float* __restrict__ X,
                                             const float* __restrict__ CB,
                                             const float* __restrict__ xx,
                                             const float* __restrict__ cbn,
                                             int row, int col,
                                             u64* __restrict__ best) {
    const float4* xp = (const float4*)(X + (size_t)row * COLS);
    const float4* cp = (const float4*)(CB + (size_t)col * COLS);
    float d = 0.f;
    #pragma unroll 8
    for (int q = 0; q < 64; ++q) {
        float4 a = xp[q], b = cp[q];
        d = fmaf(a.x, b.x, d); d = fmaf(a.y, b.y, d);
        d = fmaf(a.z, b.z, d); d = fmaf(a.w, b.w, d);
    }
    float d2e = fmaf(-2.f, d, xx[row]) + cbn[col];
    u64 pk = ((u64)f32_sortable(d2e) << 32) | (u32)col;
    atomicMin(&best[row], pk);
}

// ---------- kernel 0: xx[r], X->bf16 (linear), init best/cbn_max ----------
__global__ __launch_bounds__(256) void k_prep(const float* __restrict__ X,
                                              short* __restrict__ Xh,
                                              float* __restrict__ xx,
                                              u64* __restrict__ best,
                                              u32* __restrict__ cbn_max) {
    int r    = blockIdx.x * 4 + (threadIdx.x >> 6);
    int lane = threadIdx.x & 63;
    float4 v = *reinterpret_cast<const float4*>(X + (size_t)r * COLS + lane * 4);
    uint2 p; p.x = pk2(v.x, v.y); p.y = pk2(v.z, v.w);
    *reinterpret_cast<uint2*>(Xh + (size_t)r * COLS + lane * 4) = p;
    float s = wave_sum(v.x*v.x + v.y*v.y + v.z*v.z + v.w*v.w);
    if (lane == 0) { xx[r] = s; best[r] = ~0ull; }
    if (blockIdx.x == 0 && threadIdx.x == 0) *cbn_max = 0u;
}

// ---------- kernel 1: codebook fp32 + FRAGMENT-ORDER bf16 + |cb|^2 ----------
// CBf layout: fragment f = bn*64 + kb*16 + ks*8 + ni holds 64 lanes x 8 bf16:
// lane l = (k_hi)*16 + (code&15), data = code row (bn*128+ni*16+(code&15)),
// k = kb*64 + (ks*4 + k_hi)*8 .. +8.  Screen loads it with ONE coalesced
// global_load_dwordx4 per fragment (no LDS, no barriers).
__global__ __launch_bounds__(256) void k_codebook(const float* __restrict__ fc,
                                                  const float* __restrict__ Wi,
                                                  const float* __restrict__ Wo,
                                                  float* __restrict__ CB,
                                                  short* __restrict__ CBf,
                                                  float* __restrict__ cbn,
                                                  u32* __restrict__ cbn_max) {
    int n = blockIdx.x, tid = threadIdx.x;
    int o = tid >> 4, k = tid & 15;
    __shared__ float fcs[256], wis[256], wos[256], hs[256], sq[256];
    __shared__ short cvs_sh[256];
    fcs[tid] = fc[(size_t)n * 256 + tid];
    wis[tid] = Wi[tid];
    wos[tid] = Wo[tid];
    __syncthreads();
    float hp = 0.f;
    #pragma unroll
    for (int i = 0; i < 16; ++i) hp = fmaf(wis[o*16 + i], fcs[i*16 + k], hp);
    hs[tid] = hp;
    __syncthreads();
    float h0 = hs[o * 16];
    float x3 = h0 * h0 * h0;
    float inner = 0.7978845608028654f * fmaf(0.044715f, x3, h0);
    float g = 0.5f * h0 * (1.f + tanhf(inner));
    float hg = hp * g;
    __syncthreads();
    hs[tid] = hg;
    __syncthreads();
    float cv = 0.f;
    #pragma unroll
    for (int i = 0; i < 16; ++i) cv = fmaf(wos[o*16 + i], hs[i*16 + k], cv);
    CB[(size_t)n * 256 + tid] = cv;
    { union { __hip_bfloat16 h; short s; } c; c.h = __float2bfloat16(cv);
      cvs_sh[tid] = c.s; }
    sq[tid] = cv * cv;
    __syncthreads();
    #pragma unroll
    for (int st = 128; st > 0; st >>= 1) {
        if (tid < st) sq[tid] += sq[tid + st];
        __syncthreads();
    }
    if (tid == 0) { cbn[n] = sq[0]; atomicMax(cbn_max, __float_as_uint(sq[0])); }
    // swizzled write: 32 chunks of 8 bf16 -> fragment slots
    if (tid < 32) {
        int kc = tid;                          // global 8-short chunk 0..31
        int bn = n >> 7, ni = (n >> 4) & 7, rl = n & 15;
        int kb = kc >> 3, kgl = kc & 7, ks = kgl >> 2, khi = kgl & 3;
        int lane = khi * 16 + rl;
        size_t off = ((size_t)(bn * 64 + kb * 16 + ks * 8 + ni) * 64 + lane) * 8;
        *reinterpret_cast<uint4*>(CBf + off) =
            *reinterpret_cast<const uint4*>(&cvs_sh[kc * 8]);
    }
}

// ---------- kernel 2: barrier-free register-direct screen ----------
// 512 blocks x 256 threads; wave w owns 32 rows (mi=2 x 16). A held fully in
// regs (af[2][8]); B fragments loaded per tile with 64 coalesced
// global_load_dwordx4 from the fragment-ordered CBf (L1/L2-resident, 2 MiB).
// No LDS staging, no barriers: each wave self-paced, compiler pipelines
// loads under 128 MFMAs/tile. Per-(mi,rg) epilogue: running row-min (shfl
// over lane&15 group) + candidate collect vs thr = rmin + delta (running-min
// collection is safe: d2a(c*) <= m_run + 2*err <= m_run + delta, so the true
// argmin and all exact ties always enter). Candidates -> LDS ring [16][256]
// (lane-consecutive, rare writes); exact fp32 rerank after the loop;
// >16/lane overflow falls back inline (extra vmem only ADDS strictness).
__global__ __launch_bounds__(256, 2) void k_screen_fused(
        const short* __restrict__ Xh,
        const short* __restrict__ CBf,
        const float* __restrict__ X,
        const float* __restrict__ CB,
        const float* __restrict__ cbn,
        const float* __restrict__ xx,
        u64* __restrict__ best,
        const u32* __restrict__ cbn_max) {
    __shared__ float cbn_s[Nn];          // 16 KB
    __shared__ u32 cand_lds[16][256];    // 16 KB, [slot][tid]

    const int tid  = threadIdx.x;
    const int lane = tid & 63;
    const int w    = tid >> 6;           // wave 0..3
    const int bmBase = blockIdx.x * 128; // 32 rows per wave

    // cbn -> LDS (all 4096 codes)
    #pragma unroll
    for (int j = 0; j < 4; ++j)
        *reinterpret_cast<float4*>(&cbn_s[tid * 16 + j * 4]) =
            *reinterpret_cast<const float4*>(&cbn[tid * 16 + j * 4]);

    // A fragments: af[mi][kq], rows bmBase + w*32 + mi*16 + (lane&15)
    bf16x8 af[2][8];
    #pragma unroll
    for (int mi = 0; mi < 2; ++mi) {
        int arow = bmBase + w * 32 + mi * 16 + (lane & 15);
        const short* ap = Xh + ((size_t)arow << 8) + (lane >> 4) * 8;
        #pragma unroll
        for (int kq = 0; kq < 8; ++kq)
            af[mi][kq] = *reinterpret_cast<const bf16x8*>(ap + kq * 32);
    }
    float xxv[2][4], dlt[2][4], rmin[2][4];
    const float cmax = __uint_as_float(*cbn_max);
    #pragma unroll
    for (int mi = 0; mi < 2; ++mi)
        #pragma unroll
        for (int rg = 0; rg < 4; ++rg) {
            xxv[mi][rg] = xx[bmBase + w * 32 + mi * 16 + (lane >> 4) * 4 + rg];
            dlt[mi][rg] = fmaf(0.003f, sqrtf(xxv[mi][rg] * cmax), 0.01f);
            rmin[mi][rg] = 1e30f;
        }
    __syncthreads();        // cbn_s visible (only barrier in the kernel)

    int ccnt = 0;
    for (int bn = 0; bn < 32; ++bn) {
        f32x4 acc[2][8];
        #pragma unroll
        for (int mi = 0; mi < 2; ++mi)
            #pragma unroll
            for (int ni = 0; ni < 8; ++ni) acc[mi][ni] = f32x4{0.f, 0.f, 0.f, 0.f};

        const short* tb = CBf + (size_t)bn * 32768 + lane * 8;  // 64 frags x 512
        #pragma unroll
        for (int kq = 0; kq < 8; ++kq) {         // kb*2+ks
            bf16x8 bfv[8];
            const short* fb = tb + kq * 4096;
            #pragma unroll
            for (int ni = 0; ni < 8; ++ni)
                bfv[ni] = *reinterpret_cast<const bf16x8*>(fb + ni * 512);
            #pragma unroll
            for (int ni = 0; ni < 8; ++ni) {
                acc[0][ni] = __builtin_amdgcn_mfma_f32_16x16x32_bf16(
                    af[0][kq], bfv[ni], acc[0][ni], 0, 0, 0);
                acc[1][ni] = __builtin_amdgcn_mfma_f32_16x16x32_bf16(
                    af[1][kq], bfv[ni], acc[1][ni], 0, 0, 0);
            }
        }

        // epilogue: per-(mi,rg) to keep register pressure flat
        float cb_v[8];
        #pragma unroll
        for (int ni = 0; ni < 8; ++ni)
            cb_v[ni] = cbn_s[bn * 128 + ni * 16 + (lane & 15)];
        #pragma unroll
        for (int mi = 0; mi < 2; ++mi) {
            #pragma unroll
            for (int rg = 0; rg < 4; ++rg) {
                float d2v[8], m = 1e30f;
                #pragma unroll
                for (int ni = 0; ni < 8; ++ni) {
                    d2v[ni] = fmaf(-2.f, acc[mi][ni][rg], xxv[mi][rg]) + cb_v[ni];
                    m = fminf(m, d2v[ni]);
                }
                #pragma unroll
                for (int d = 1; d < 16; d <<= 1)
                    m = fminf(m, __shfl_xor(m, d, 64));
                rmin[mi][rg] = fminf(rmin[mi][rg], m);   // running min incl. tile
                float thr = rmin[mi][rg] + dlt[mi][rg];
                #pragma unroll
                for (int ni = 0; ni < 8; ++ni) {
                    if (d2v[ni] <= thr) {
                        u32 enc = ((u32)(mi * 4 + rg) << 16)
                                | (u32)(bn * 128 + ni * 16 + (lane & 15));
                        if (ccnt < 16) cand_lds[ccnt][tid] = enc;
                        else exact_rerank(X, CB, xx, cbn,   // ~never: stricter only
                                 bmBase + w * 32 + mi * 16 + (lane >> 4) * 4 + rg,
                                 bn * 128 + ni * 16 + (lane & 15), best);
                        ++ccnt;
                    }
                }
            }
        }
    }

    // post-loop: exact fp32 rerank of buffered candidates (R2's tree)
    int nc = ccnt < 16 ? ccnt : 16;
    for (int i = 0; i < nc; ++i) {
        u32 e = cand_lds[i][tid];
        int em = (int)(e >> 16), mi = em >> 2, rg = em & 3;
        int row = bmBase + w * 32 + mi * 16 + (lane >> 4) * 4 + rg;
        exact_rerank(X, CB, xx, cbn, row, (int)(e & 0xFFFF), best);
    }
}

// ---------- kernel 3: gather e, Householder STE ----------
__global__ __launch_bounds__(256) void k_epilogue(const float* __restrict__ X,
                                                  const float* __restrict__ CB,
                                                  const u64* __restrict__ best,
                                                  float* __restrict__ Eout,
                                                  float* __restrict__ Sout) {
    int r    = blockIdx.x * 4 + (threadIdx.x >> 6);
    int lane = threadIdx.x & 63;
    int idx  = (int)(best[r] & 0xffffffffull);

    float4 xv = *reinterpret_cast<const float4*>(X  + (size_t)r   * COLS + lane * 4);
    float4 ev = *reinterpret_cast<const float4*>(CB + (size_t)idx * COLS + lane * 4);

    float xn2 = wave_sum(dot4(xv, xv));
    float en2 = wave_sum(dot4(ev, ev));
    float xn = sqrtf(xn2), en = sqrtf(en2);
    float invx = 1.f / fmaxf(xn, EPSF);
    float inve = 1.f / fmaxf(en, EPSF);

    float4 xd, ed, sd0;
    xd.x = xv.x*invx; xd.y = xv.y*invx; xd.z = xv.z*invx; xd.w = xv.w*invx;
    ed.x = ev.x*inve; ed.y = ev.y*inve; ed.z = ev.z*inve; ed.w = ev.w*inve;
    sd0.x = xd.x+ed.x; sd0.y = xd.y+ed.y; sd0.z = xd.z+ed.z; sd0.w = xd.w+ed.w;

    float sdn2 = wave_sum(dot4(sd0, sd0));
    float p1   = wave_sum(dot4(sd0, xv));
    float p2   = wave_sum(dot4(xd,  xv));
    float invs = 1.f / fmaxf(sqrtf(sdn2), EPSF);

    float csd = -2.f * invs * invs * p1;
    float ced =  2.f * p2;
    float4 rr;
    rr.x = fmaf(csd, sd0.x, fmaf(ced, ed.x, xv.x));
    rr.y = fmaf(csd, sd0.y, fmaf(ced, ed.y, xv.y));
    rr.z = fmaf(csd, sd0.z, fmaf(ced, ed.z, xv.z));
    rr.w = fmaf(csd, sd0.w, fmaf(ced, ed.w, xv.w));
    float sc = en * invx;
    float4 sv; sv.x = rr.x*sc; sv.y = rr.y*sc; sv.z = rr.z*sc; sv.w = rr.w*sc;

    *reinterpret_cast<float4*>(Eout + (size_t)r * COLS + lane * 4) = ev;
    *reinterpret_cast<float4*>(Sout + (size_t)r * COLS + lane * 4) = sv;
}

// ---------- launcher ----------
extern "C" void kernel_launch(void* const* d_in, const int* in_sizes, int n_in,
                              void* d_out, int out_size, void* d_ws, size_t ws_size,
                              hipStream_t stream) {
    const float* x  = (const float*)d_in[0];
    const float* fc = (const float*)d_in[1];
    const float* Wi = (const float*)d_in[2];
    const float* Wo = (const float*)d_in[3];

    // ws layout (~5 MB)
    char* ws = (char*)d_ws;
    u64*   best    = (u64*)ws;                            ws += (size_t)ROWS * 8;
    float* CBws    = (float*)ws;                          ws += (size_t)Nn * COLS * 4;
    float* cbn     = (float*)ws;                          ws += (size_t)Nn * 4;
    float* xx      = (float*)ws;                          ws += (size_t)ROWS * 4;
    u32*   cbn_max = (u32*)ws;

    // bf16 copies live in d_out (128 MiB), only overwritten by k_epilogue at
    // the very end: Xh = 32 MiB at offset 0, CBf = 2 MiB at offset 64 MiB.
    short* Xh  = (short*)d_out;
    short* CBf = (short*)((char*)d_out + (64u << 20));

    float* Eout = (float*)d_out;
    float* Sout = Eout + (size_t)ROWS * COLS;

    k_prep<<<ROWS / 4, 256, 0, stream>>>(x, Xh, xx, best, cbn_max);
    k_codebook<<<Nn, 256, 0, stream>>>(fc, Wi, Wo, CBws, CBf, cbn, cbn_max);
    k_screen_fused<<<ROWS / 128, 256, 0, stream>>>(Xh, CBf, x, CBws, cbn, xx, best, cbn_max);
    k_epilogue<<<ROWS / 4, 256, 0, stream>>>(x, CBws, best, Eout, Sout);
}